// Round 1
// baseline (947.918 us; speedup 1.0000x reference)
//
#include <hip/hip_runtime.h>
#include <stdint.h>

#define D 128
#define K1 384
#define TM 128
#define N_EDGES 800000
#define N_NODES 50000

typedef __attribute__((ext_vector_type(8))) short short8;   // 8 bf16 = 4 VGPRs
typedef __attribute__((ext_vector_type(4))) float f32x4;
typedef unsigned int u32;

__device__ __forceinline__ u32 bf16_rne(float f) {
    u32 u = __builtin_bit_cast(u32, f);
    return (u + 0x7FFFu + ((u >> 16) & 1u)) >> 16;
}
__device__ __forceinline__ u32 pk2(float lo, float hi) {
    return bf16_rne(lo) | (bf16_rne(hi) << 16);
}

// ---- prep: cell_attr fp32 -> bf16 (flat, vectorized) ----
__global__ void prep_cell(const float* __restrict__ src, unsigned short* __restrict__ dst, int n4) {
    int i = blockIdx.x * blockDim.x + threadIdx.x;
    if (i >= n4) return;
    float4 v = ((const float4*)src)[i];
    ushort4 o;
    o.x = (unsigned short)bf16_rne(v.x);
    o.y = (unsigned short)bf16_rne(v.y);
    o.z = (unsigned short)bf16_rne(v.z);
    o.w = (unsigned short)bf16_rne(v.w);
    ((ushort4*)dst)[i] = o;
}

// ---- prep: W1 (384x128) -> W1T bf16 (128x384), W2 (128x128) -> W2T bf16 (128x128) ----
__global__ void prep_w(const float* __restrict__ W1, const float* __restrict__ W2,
                       unsigned short* __restrict__ W1T, unsigned short* __restrict__ W2T) {
    int id = blockIdx.x * blockDim.x + threadIdx.x;   // 0 .. 65535
    if (id < K1 * D) {
        int n = id & 127, k = id >> 7;                // id = k*128 + n
        W1T[n * K1 + k] = (unsigned short)bf16_rne(W1[id]);
    } else {
        int id2 = id - K1 * D;
        int n = id2 & 127, k = id2 >> 7;
        W2T[n * D + k] = (unsigned short)bf16_rne(W2[id2]);
    }
}

// ---- fused gather + MLP, barrier-free direct-to-fragment version ----
// Wave grid 2x2: wave (wm,wn) computes out quadrant rows [wm*64,+64) x cols [wn*64,+64).
// All MFMAs use swapped operands: mfma(Wfrag, Afrag, acc) -> D[n on q*4+r][m on l16].
// A-operands (cell gathers / edge rows) load straight into fragments from global.
// W-operands load straight from L2-resident W1T/W2T, prefetched one chunk ahead.
// Only LDS: 32KB swizzled h buffer for the GEMM1->GEMM2 transpose; ONE __syncthreads.
template <bool CELL_BF16>
__global__ __launch_bounds__(256, 2) void edge_mlp(
    const float* __restrict__ cell_f32,
    const unsigned short* __restrict__ cellb,
    const float* __restrict__ edge_attr,
    const unsigned short* __restrict__ W1T,   // [128][384] bf16
    const float* __restrict__ b1,
    const unsigned short* __restrict__ W2T,   // [128][128] bf16
    const float* __restrict__ b2,
    const int* __restrict__ sidx,
    const int* __restrict__ ridx,
    float* __restrict__ out)
{
    __shared__ __align__(16) unsigned short sH[TM * D];   // 32 KB, XOR-swizzled

    const int tid  = threadIdx.x;
    const int lane = tid & 63;
    const int wave = tid >> 6;
    const int l16  = lane & 15;
    const int q    = lane >> 4;
    const int wm   = wave >> 1;          // m-half (edge rows)
    const int wn   = wave & 1;           // n-half (out cols / W rows)
    const int e0   = blockIdx.x * TM;
    const int mrow = wm * 64 + l16;      // + mt*16
    const int ncol = wn * 64 + l16;      // + nt*16

    // ---- indices for this lane's 4 m-tiles (quads redundant -> broadcast) ----
    int idxs[4], idxr[4];
#pragma unroll
    for (int mt = 0; mt < 4; ++mt) {
        idxs[mt] = sidx[e0 + mrow + mt * 16];
        idxr[mt] = ridx[e0 + mrow + mt * 16];
    }

    // ---- prologue: W frags for edge chunk (k 256..383) + edge A-frags ----
    short8 wf0[4][4];
#pragma unroll
    for (int nt = 0; nt < 4; ++nt) {
        const unsigned short* wp = W1T + (size_t)(ncol + nt * 16) * K1 + 256 + q * 8;
#pragma unroll
        for (int kk = 0; kk < 4; ++kk) wf0[nt][kk] = *(const short8*)(wp + kk * 32);
    }
    short8 aE[4][4];
#pragma unroll
    for (int mt = 0; mt < 4; ++mt) {
        const float* p = edge_attr + (size_t)(e0 + mrow + mt * 16) * D + q * 8;
#pragma unroll
        for (int kk = 0; kk < 4; ++kk) {
            float4 f0 = *(const float4*)(p + kk * 32);
            float4 f1 = *(const float4*)(p + kk * 32 + 4);
            uint4 v = make_uint4(pk2(f0.x, f0.y), pk2(f0.z, f0.w), pk2(f1.x, f1.y), pk2(f1.z, f1.w));
            aE[mt][kk] = __builtin_bit_cast(short8, v);
        }
    }

    f32x4 acc[4][4];
#pragma unroll
    for (int i = 0; i < 4; ++i)
#pragma unroll
        for (int j = 0; j < 4; ++j) acc[i][j] = (f32x4){0.f, 0.f, 0.f, 0.f};

    short8 aS[4][4], aR[4][4], wf1[4][4], wf2[4][4], w2f[4][4];

    // ---------------- chunk 0: edge (k 256..383); prefetch senders ----------------
#pragma unroll
    for (int kk = 0; kk < 4; ++kk) {
#pragma unroll
        for (int nt = 0; nt < 4; ++nt)   // prefetch W1 senders chunk (kb=0)
            wf1[nt][kk] = *(const short8*)(W1T + (size_t)(ncol + nt * 16) * K1 + kk * 32 + q * 8);
#pragma unroll
        for (int mt = 0; mt < 4; ++mt) { // prefetch sender gathers
            if constexpr (CELL_BF16) {
                aS[mt][kk] = *(const short8*)(cellb + (size_t)idxs[mt] * D + kk * 32 + q * 8);
            } else {
                const float* gp = cell_f32 + (size_t)idxs[mt] * D + kk * 32 + q * 8;
                float4 f0 = *(const float4*)gp; float4 f1 = *(const float4*)(gp + 4);
                uint4 v = make_uint4(pk2(f0.x, f0.y), pk2(f0.z, f0.w), pk2(f1.x, f1.y), pk2(f1.z, f1.w));
                aS[mt][kk] = __builtin_bit_cast(short8, v);
            }
        }
#pragma unroll
        for (int nt = 0; nt < 4; ++nt)
#pragma unroll
            for (int mt = 0; mt < 4; ++mt)
                acc[nt][mt] = __builtin_amdgcn_mfma_f32_16x16x32_bf16(wf0[nt][kk], aE[mt][kk], acc[nt][mt], 0, 0, 0);
    }

    // ---------------- chunk 1: senders (k 0..127); prefetch receivers ----------------
#pragma unroll
    for (int kk = 0; kk < 4; ++kk) {
#pragma unroll
        for (int nt = 0; nt < 4; ++nt)   // prefetch W1 receivers chunk (kb=128)
            wf2[nt][kk] = *(const short8*)(W1T + (size_t)(ncol + nt * 16) * K1 + 128 + kk * 32 + q * 8);
#pragma unroll
        for (int mt = 0; mt < 4; ++mt) { // prefetch receiver gathers
            if constexpr (CELL_BF16) {
                aR[mt][kk] = *(const short8*)(cellb + (size_t)idxr[mt] * D + kk * 32 + q * 8);
            } else {
                const float* gp = cell_f32 + (size_t)idxr[mt] * D + kk * 32 + q * 8;
                float4 f0 = *(const float4*)gp; float4 f1 = *(const float4*)(gp + 4);
                uint4 v = make_uint4(pk2(f0.x, f0.y), pk2(f0.z, f0.w), pk2(f1.x, f1.y), pk2(f1.z, f1.w));
                aR[mt][kk] = __builtin_bit_cast(short8, v);
            }
        }
#pragma unroll
        for (int nt = 0; nt < 4; ++nt)
#pragma unroll
            for (int mt = 0; mt < 4; ++mt)
                acc[nt][mt] = __builtin_amdgcn_mfma_f32_16x16x32_bf16(wf1[nt][kk], aS[mt][kk], acc[nt][mt], 0, 0, 0);
    }

    // bias fragments (16B loads, L1-broadcast within quads)
    f32x4 b1v[4], b2v[4];
#pragma unroll
    for (int nt = 0; nt < 4; ++nt) {
        b1v[nt] = *(const f32x4*)(b1 + wn * 64 + nt * 16 + q * 4);
        b2v[nt] = *(const f32x4*)(b2 + wn * 64 + nt * 16 + q * 4);
    }

    // ---------------- chunk 2: receivers (k 128..255); prefetch W2 ----------------
#pragma unroll
    for (int kk = 0; kk < 4; ++kk) {
#pragma unroll
        for (int nt = 0; nt < 4; ++nt)   // prefetch W2 frags for GEMM2
            w2f[nt][kk] = *(const short8*)(W2T + (size_t)(ncol + nt * 16) * D + kk * 32 + q * 8);
#pragma unroll
        for (int nt = 0; nt < 4; ++nt)
#pragma unroll
            for (int mt = 0; mt < 4; ++mt)
                acc[nt][mt] = __builtin_amdgcn_mfma_f32_16x16x32_bf16(wf2[nt][kk], aR[mt][kk], acc[nt][mt], 0, 0, 0);
    }

    // ---------------- h = relu(acc + b1) -> swizzled LDS (packed b64 writes) ----------------
    // lane holds h[m = wm*64+mt*16+l16][n = wn*64+nt*16+q*4+r]; 16B-slot s = n>>3, s ^= (M&7)
#pragma unroll
    for (int nt = 0; nt < 4; ++nt)
#pragma unroll
        for (int mt = 0; mt < 4; ++mt) {
            f32x4 v = acc[nt][mt] + b1v[nt];
#pragma unroll
            for (int r = 0; r < 4; ++r) v[r] = v[r] > 0.f ? v[r] : 0.f;
            u32 lo = pk2(v[0], v[1]);
            u32 hi = pk2(v[2], v[3]);
            int M = wm * 64 + mt * 16 + l16;
            int slot = (wn * 8 + nt * 2 + (q >> 1)) ^ (M & 7);
            *(uint2*)((char*)sH + M * 256 + slot * 16 + (q & 1) * 8) = make_uint2(lo, hi);
        }
    __syncthreads();   // the only barrier: h halves exchanged between wn-pairs

    // ---------------- GEMM2: out = h @ W2 + b2 (swapped operands) ----------------
    f32x4 acc2[4][4];
#pragma unroll
    for (int i = 0; i < 4; ++i)
#pragma unroll
        for (int j = 0; j < 4; ++j) acc2[i][j] = (f32x4){0.f, 0.f, 0.f, 0.f};

#pragma unroll
    for (int kk = 0; kk < 4; ++kk) {
        short8 hf[4];
#pragma unroll
        for (int mt = 0; mt < 4; ++mt) {  // h^T frag: lane reads h[M][kk*32+q*8 ..+8]
            int M = wm * 64 + mt * 16 + l16;
            int slot = (kk * 4 + q) ^ (M & 7);
            hf[mt] = *(const short8*)((const char*)sH + M * 256 + slot * 16);
        }
#pragma unroll
        for (int nt = 0; nt < 4; ++nt)
#pragma unroll
            for (int mt = 0; mt < 4; ++mt)
                acc2[nt][mt] = __builtin_amdgcn_mfma_f32_16x16x32_bf16(w2f[nt][kk], hf[mt], acc2[nt][mt], 0, 0, 0);
    }

    // ---------------- epilogue: + b2, coalesced float4 stores ----------------
#pragma unroll
    for (int nt = 0; nt < 4; ++nt)
#pragma unroll
        for (int mt = 0; mt < 4; ++mt) {
            f32x4 o = acc2[nt][mt] + b2v[nt];
            *(f32x4*)(out + (size_t)(e0 + mrow + mt * 16) * D + wn * 64 + nt * 16 + q * 4) = o;
        }
}

extern "C" void kernel_launch(void* const* d_in, const int* in_sizes, int n_in,
                              void* d_out, int out_size, void* d_ws, size_t ws_size,
                              hipStream_t stream) {
    const float* cell = (const float*)d_in[0];
    const float* edge = (const float*)d_in[1];
    const float* W1   = (const float*)d_in[2];
    const float* b1   = (const float*)d_in[3];
    const float* W2   = (const float*)d_in[4];
    const float* b2   = (const float*)d_in[5];
    const int*   eidx = (const int*)d_in[6];

    const size_t cell_bytes = (size_t)N_NODES * D * 2;      // 12.8 MB
    const size_t w1t_bytes  = (size_t)K1 * D * 2;           // 98304
    const size_t w2t_bytes  = (size_t)D * D * 2;            // 32768

    bool cell_in_ws = ws_size >= cell_bytes + w1t_bytes + w2t_bytes;
    unsigned short* cellb;
    unsigned short* W1T;
    if (cell_in_ws) {
        cellb = (unsigned short*)d_ws;
        W1T   = (unsigned short*)((char*)d_ws + cell_bytes);
    } else {
        cellb = nullptr;
        W1T   = (unsigned short*)d_ws;
    }
    unsigned short* W2T = W1T + K1 * D;

    if (cell_in_ws) {
        int n4 = N_NODES * D / 4;   // 1.6M float4s
        prep_cell<<<(n4 + 255) / 256, 256, 0, stream>>>(cell, cellb, n4);
    }
    prep_w<<<(K1 * D + D * D) / 256, 256, 0, stream>>>(W1, W2, W1T, W2T);

    const int* sidx = eidx;
    const int* ridx = eidx + N_EDGES;
    if (cell_in_ws) {
        edge_mlp<true><<<N_EDGES / TM, 256, 0, stream>>>(
            cell, cellb, edge, W1T, b1, W2T, b2, sidx, ridx, (float*)d_out);
    } else {
        edge_mlp<false><<<N_EDGES / TM, 256, 0, stream>>>(
            cell, cellb, edge, W1T, b1, W2T, b2, sidx, ridx, (float*)d_out);
    }
}

// Round 2
// 810.222 us; speedup vs baseline: 1.1699x; 1.1699x over previous
//
#include <hip/hip_runtime.h>
#include <stdint.h>

#define D 128
#define K1 384
#define TM 128
#define N_EDGES 800000
#define N_NODES 50000

typedef __attribute__((ext_vector_type(8))) short short8;   // 8 bf16 = 4 VGPRs
typedef __attribute__((ext_vector_type(4))) float f32x4;
typedef unsigned int u32;

__device__ __forceinline__ u32 bf16_rne(float f) {
    u32 u = __builtin_bit_cast(u32, f);
    return (u + 0x7FFFu + ((u >> 16) & 1u)) >> 16;
}
__device__ __forceinline__ u32 pk2(float lo, float hi) {
    return bf16_rne(lo) | (bf16_rne(hi) << 16);
}

// async global->LDS DMA, 16B per lane. LDS dest = wave-uniform base + lane*16.
__device__ __forceinline__ void gl_lds16(const void* g, void* l) {
    __builtin_amdgcn_global_load_lds(
        (const __attribute__((address_space(1))) void*)g,
        (__attribute__((address_space(3))) void*)l,
        16, 0, 0);
}

// ---- prep: cell_attr fp32 -> bf16 (flat, vectorized) ----
__global__ void prep_cell(const float* __restrict__ src, unsigned short* __restrict__ dst, int n4) {
    int i = blockIdx.x * blockDim.x + threadIdx.x;
    if (i >= n4) return;
    float4 v = ((const float4*)src)[i];
    ushort4 o;
    o.x = (unsigned short)bf16_rne(v.x);
    o.y = (unsigned short)bf16_rne(v.y);
    o.z = (unsigned short)bf16_rne(v.z);
    o.w = (unsigned short)bf16_rne(v.w);
    ((ushort4*)dst)[i] = o;
}

// ---- prep: W1/W2 -> FRAGMENT-ORDERED bf16 arrays ----
// W1F: [c][kk][wn][nt][lane]x8  (c=k/128, kk=(k%128)/32, q=(k%32)/8, e=k%8; lane=q*16+l16, l16=n%16)
// A wave's MFMA A-operand frag (16 rows x 32 k) = 64 lanes x 16B CONTIGUOUS -> 1KB coalesced load.
__global__ void prep_w(const float* __restrict__ W1, const float* __restrict__ W2,
                       unsigned short* __restrict__ W1F, unsigned short* __restrict__ W2F) {
    int id = blockIdx.x * blockDim.x + threadIdx.x;   // 0 .. 65535
    if (id < K1 * D) {
        int k = id >> 7, n = id & 127;
        int c = k >> 7, kr = k & 127;
        int kk = kr >> 5, q = (kr >> 3) & 3, e = kr & 7;
        int wn = n >> 6, nt = (n >> 4) & 3, l16 = n & 15;
        int seg = (((c * 4 + kk) * 2 + wn) * 4 + nt) * 64 + q * 16 + l16;
        W1F[seg * 8 + e] = (unsigned short)bf16_rne(W1[id]);
    } else {
        int id2 = id - K1 * D;
        int k = id2 >> 7, n = id2 & 127;
        int kk = k >> 5, q = (k >> 3) & 3, e = k & 7;
        int wn = n >> 6, nt = (n >> 4) & 3, l16 = n & 15;
        int seg = ((kk * 2 + wn) * 4 + nt) * 64 + q * 16 + l16;
        W2F[seg * 8 + e] = (unsigned short)bf16_rne(W2[id2]);
    }
}

// ---- fused gather + MLP ----
// Wave grid 2x2: wave (wm,wn) owns out rows [wm*64,+64) x cols [wn*64,+64).
// Swapped MFMA: mfma(Wfrag, Afrag, acc) -> D[n on q*4+r][m on l16].
// One 32KB XOR-swizzled sA holds sender/receiver/edge chunk in turn, then h.
// Cell chunks staged by global_load_lds DMA (linear dest + inverse-swizzled per-lane source);
// edge chunk reg-staged (fp32->bf16) with async load-early/write-late split.
template <bool CELL_BF16>
__global__ __launch_bounds__(256, 2) void edge_mlp(
    const float* __restrict__ cell_f32,
    const unsigned short* __restrict__ cellb,
    const float* __restrict__ edge_attr,
    const unsigned short* __restrict__ W1F,
    const float* __restrict__ b1,
    const unsigned short* __restrict__ W2F,
    const float* __restrict__ b2,
    const int* __restrict__ sidx,
    const int* __restrict__ ridx,
    float* __restrict__ out)
{
    __shared__ __align__(16) unsigned short sA[TM * D];   // 32 KB, 16B-slot XOR swizzle: slot ^= row&7

    const int tid  = threadIdx.x;
    const int lane = tid & 63;
    const int wave = tid >> 6;
    const int l16  = lane & 15;
    const int q    = lane >> 4;
    const int wm   = wave >> 1;
    const int wn   = wave & 1;
    const int e0   = blockIdx.x * TM;
    const int seg  = tid & 15;         // 16B slot within a 256B row
    const int rb   = tid >> 4;         // base row 0..15

    // stage a cell chunk (gather) into sA
    auto stage_cell = [&](const int* __restrict__ idxp) {
        if constexpr (CELL_BF16) {
            // DMA: linear dest (base + lane*16), source seg pre-swizzled
            const int srcoff = (seg ^ (rb & 7)) * 8;          // elems
            char* ldst = (char*)sA + wave * 1024;
#pragma unroll
            for (int it = 0; it < 8; ++it) {
                const int node = idxp[e0 + rb + it * 16];
                gl_lds16(cellb + (size_t)node * D + srcoff, ldst + it * 4096);
            }
        } else {
            const int doff = (seg ^ (rb & 7)) * 16;           // bytes
#pragma unroll
            for (int it = 0; it < 8; ++it) {
                const int row = rb + it * 16;
                const int node = idxp[e0 + row];
                const float* src = cell_f32 + (size_t)node * D + seg * 8;
                float4 f0 = *(const float4*)src;
                float4 f1 = *(const float4*)(src + 4);
                uint4 v = make_uint4(pk2(f0.x, f0.y), pk2(f0.z, f0.w),
                                     pk2(f1.x, f1.y), pk2(f1.z, f1.w));
                *(uint4*)((char*)sA + row * 256 + doff) = v;
            }
        }
    };

    short8 af[4][4];
    auto read_frags = [&]() {
#pragma unroll
        for (int mt = 0; mt < 4; ++mt) {
            const int row = wm * 64 + mt * 16 + l16;
            const char* rp = (const char*)sA + row * 256;
            const int x = row & 7;
#pragma unroll
            for (int kk = 0; kk < 4; ++kk)
                af[mt][kk] = *(const short8*)(rp + (((kk * 4 + q) ^ x) * 16));
        }
    };

    f32x4 acc[4][4];
#pragma unroll
    for (int i = 0; i < 4; ++i)
#pragma unroll
        for (int j = 0; j < 4; ++j) acc[i][j] = (f32x4){0.f, 0.f, 0.f, 0.f};

    auto compute_chunk = [&](int c) {
#pragma unroll
        for (int kk = 0; kk < 4; ++kk) {
            short8 wf[4];
#pragma unroll
            for (int nt = 0; nt < 4; ++nt)
                wf[nt] = *(const short8*)(W1F + (size_t)((((c * 4 + kk) * 2 + wn) * 4 + nt) * 64 + lane) * 8);
#pragma unroll
            for (int nt = 0; nt < 4; ++nt)
#pragma unroll
                for (int mt = 0; mt < 4; ++mt)
                    acc[nt][mt] = __builtin_amdgcn_mfma_f32_16x16x32_bf16(wf[nt], af[mt][kk], acc[nt][mt], 0, 0, 0);
        }
    };

    // ---------------- chunk 0: senders (k 0..127) ----------------
    stage_cell(sidx);
    __syncthreads();                       // drain DMA; S in sA
    read_frags();
    __syncthreads();                       // all waves hold S frags; sA free

    stage_cell(ridx);                      // DMA receivers (overlaps c0 compute)
    compute_chunk(0);
    __syncthreads();                       // drain; R in sA

    // ---------------- chunk 1: receivers (k 128..255) ----------------
    read_frags();
    __syncthreads();                       // sA free

    // async edge stage: issue loads now, convert+write after compute
    float4 ef0[8], ef1[8];
#pragma unroll
    for (int it = 0; it < 8; ++it) {
        const float* src = edge_attr + (size_t)(e0 + rb + it * 16) * D + seg * 8;
        ef0[it] = *(const float4*)src;
        ef1[it] = *(const float4*)(src + 4);
    }
    compute_chunk(1);
    {
        const int doff = (seg ^ (rb & 7)) * 16;
#pragma unroll
        for (int it = 0; it < 8; ++it) {
            const int row = rb + it * 16;
            uint4 v = make_uint4(pk2(ef0[it].x, ef0[it].y), pk2(ef0[it].z, ef0[it].w),
                                 pk2(ef1[it].x, ef1[it].y), pk2(ef1[it].z, ef1[it].w));
            *(uint4*)((char*)sA + row * 256 + doff) = v;
        }
    }
    __syncthreads();                       // E in sA

    // ---------------- chunk 2: edge (k 256..383) ----------------
    read_frags();
    __syncthreads();                       // sA free (for h)
    compute_chunk(2);

    // ---------------- h = relu(acc + b1) -> swizzled sA (packed 8B writes) ----------------
    f32x4 b1v[4];
#pragma unroll
    for (int nt = 0; nt < 4; ++nt)
        b1v[nt] = *(const f32x4*)(b1 + wn * 64 + nt * 16 + q * 4);

#pragma unroll
    for (int nt = 0; nt < 4; ++nt)
#pragma unroll
        for (int mt = 0; mt < 4; ++mt) {
            f32x4 v = acc[nt][mt] + b1v[nt];
#pragma unroll
            for (int r = 0; r < 4; ++r) v[r] = v[r] > 0.f ? v[r] : 0.f;
            u32 lo = pk2(v[0], v[1]);
            u32 hi = pk2(v[2], v[3]);
            int M = wm * 64 + mt * 16 + l16;
            int slot = (wn * 8 + nt * 2 + (q >> 1)) ^ (M & 7);
            *(uint2*)((char*)sA + M * 256 + slot * 16 + (q & 1) * 8) = make_uint2(lo, hi);
        }
    __syncthreads();                       // h complete

    // ---------------- GEMM2: out = h @ W2 + b2 ----------------
    f32x4 acc2[4][4];
#pragma unroll
    for (int i = 0; i < 4; ++i)
#pragma unroll
        for (int j = 0; j < 4; ++j) acc2[i][j] = (f32x4){0.f, 0.f, 0.f, 0.f};

#pragma unroll
    for (int kk = 0; kk < 4; ++kk) {
        short8 w2f[4], hf[4];
#pragma unroll
        for (int nt = 0; nt < 4; ++nt)
            w2f[nt] = *(const short8*)(W2F + (size_t)(((kk * 2 + wn) * 4 + nt) * 64 + lane) * 8);
#pragma unroll
        for (int mt = 0; mt < 4; ++mt) {
            const int row = wm * 64 + mt * 16 + l16;
            hf[mt] = *(const short8*)((const char*)sA + row * 256 + (((kk * 4 + q) ^ (row & 7)) * 16));
        }
#pragma unroll
        for (int nt = 0; nt < 4; ++nt)
#pragma unroll
            for (int mt = 0; mt < 4; ++mt)
                acc2[nt][mt] = __builtin_amdgcn_mfma_f32_16x16x32_bf16(w2f[nt], hf[mt], acc2[nt][mt], 0, 0, 0);
    }

    // ---------------- epilogue: + b2, coalesced float4 stores ----------------
    f32x4 b2v[4];
#pragma unroll
    for (int nt = 0; nt < 4; ++nt)
        b2v[nt] = *(const f32x4*)(b2 + wn * 64 + nt * 16 + q * 4);

#pragma unroll
    for (int nt = 0; nt < 4; ++nt)
#pragma unroll
        for (int mt = 0; mt < 4; ++mt) {
            f32x4 o = acc2[nt][mt] + b2v[nt];
            *(f32x4*)(out + (size_t)(e0 + wm * 64 + mt * 16 + l16) * D + wn * 64 + nt * 16 + q * 4) = o;
        }
}

extern "C" void kernel_launch(void* const* d_in, const int* in_sizes, int n_in,
                              void* d_out, int out_size, void* d_ws, size_t ws_size,
                              hipStream_t stream) {
    const float* cell = (const float*)d_in[0];
    const float* edge = (const float*)d_in[1];
    const float* W1   = (const float*)d_in[2];
    const float* b1   = (const float*)d_in[3];
    const float* W2   = (const float*)d_in[4];
    const float* b2   = (const float*)d_in[5];
    const int*   eidx = (const int*)d_in[6];

    const size_t cell_bytes = (size_t)N_NODES * D * 2;      // 12.8 MB
    const size_t w1f_bytes  = (size_t)K1 * D * 2;           // 98304
    const size_t w2f_bytes  = (size_t)D * D * 2;            // 32768

    bool cell_in_ws = ws_size >= cell_bytes + w1f_bytes + w2f_bytes;
    unsigned short* cellb;
    unsigned short* W1F;
    if (cell_in_ws) {
        cellb = (unsigned short*)d_ws;
        W1F   = (unsigned short*)((char*)d_ws + cell_bytes);
    } else {
        cellb = nullptr;
        W1F   = (unsigned short*)d_ws;
    }
    unsigned short* W2F = W1F + K1 * D;

    if (cell_in_ws) {
        int n4 = N_NODES * D / 4;   // 1.6M float4s
        prep_cell<<<(n4 + 255) / 256, 256, 0, stream>>>(cell, cellb, n4);
    }
    prep_w<<<(K1 * D + D * D) / 256, 256, 0, stream>>>(W1, W2, W1F, W2F);

    const int* sidx = eidx;
    const int* ridx = eidx + N_EDGES;
    if (cell_in_ws) {
        edge_mlp<true><<<N_EDGES / TM, 256, 0, stream>>>(
            cell, cellb, edge, W1F, b1, W2F, b2, sidx, ridx, (float*)d_out);
    } else {
        edge_mlp<false><<<N_EDGES / TM, 256, 0, stream>>>(
            cell, cellb, edge, W1F, b1, W2F, b2, sidx, ridx, (float*)d_out);
    }
}

// Round 3
// 770.027 us; speedup vs baseline: 1.2310x; 1.0522x over previous
//
#include <hip/hip_runtime.h>
#include <stdint.h>

#define D 128
#define K1 384
#define TM 64
#define N_EDGES 800000
#define N_NODES 50000

typedef __attribute__((ext_vector_type(8))) short short8;   // 8 bf16 = 4 VGPRs
typedef __attribute__((ext_vector_type(4))) float f32x4;
typedef unsigned int u32;

__device__ __forceinline__ u32 bf16_rne(float f) {
    u32 u = __builtin_bit_cast(u32, f);
    return (u + 0x7FFFu + ((u >> 16) & 1u)) >> 16;
}
__device__ __forceinline__ u32 pk2(float lo, float hi) {
    return bf16_rne(lo) | (bf16_rne(hi) << 16);
}

// async global->LDS DMA, 16B per lane; LDS dest = wave-uniform base + lane*16.
__device__ __forceinline__ void gl_lds16(const void* g, void* l) {
    __builtin_amdgcn_global_load_lds(
        (const __attribute__((address_space(1))) void*)g,
        (__attribute__((address_space(3))) void*)l,
        16, 0, 0);
}

// ---- prep: cell_attr fp32 -> bf16 (flat, vectorized) ----
__global__ void prep_cell(const float* __restrict__ src, unsigned short* __restrict__ dst, int n4) {
    int i = blockIdx.x * blockDim.x + threadIdx.x;
    if (i >= n4) return;
    float4 v = ((const float4*)src)[i];
    ushort4 o;
    o.x = (unsigned short)bf16_rne(v.x);
    o.y = (unsigned short)bf16_rne(v.y);
    o.z = (unsigned short)bf16_rne(v.z);
    o.w = (unsigned short)bf16_rne(v.w);
    ((ushort4*)dst)[i] = o;
}

// ---- prep: W1/W2 -> fragment-ordered bf16 ----
// W1F[((c*4+kk)*8 + TN)*64 + qq*16 + l16][e] = W1[c*128+kk*32+qq*8+e][TN*16+l16]
// -> a wave's frag (cols TN*16.., k-slice kk*32..) = 64 lanes x 16B contiguous.
__global__ void prep_w(const float* __restrict__ W1, const float* __restrict__ W2,
                       unsigned short* __restrict__ W1F, unsigned short* __restrict__ W2F) {
    int id = blockIdx.x * blockDim.x + threadIdx.x;   // 0 .. 65535
    if (id < K1 * D) {
        int k = id >> 7, n = id & 127;
        int c = k >> 7, kr = k & 127;
        int kk = kr >> 5, qq = (kr >> 3) & 3, e = k & 7;
        int TN = n >> 4, l16 = n & 15;
        int seg = ((c * 4 + kk) * 8 + TN) * 64 + qq * 16 + l16;
        W1F[seg * 8 + e] = (unsigned short)bf16_rne(W1[id]);
    } else {
        int id2 = id - K1 * D;
        int k = id2 >> 7, n = id2 & 127;
        int kk = k >> 5, qq = (k >> 3) & 3, e = k & 7;
        int TN = n >> 4, l16 = n & 15;
        int seg = (kk * 8 + TN) * 64 + qq * 16 + l16;
        W2F[seg * 8 + e] = (unsigned short)bf16_rne(W2[id2]);
    }
}

// ---- fused gather + MLP ----
// TM=64 edges/block; 4 waves, wave w owns all 64 rows x cols [w*32, w*32+32).
// Swapped MFMA: mfma(Wfrag, Afrag, acc) -> D[n on q*4+r][m on l16].
// Double-buffered 2x16KB LDS; 4 barriers; W-frags prefetched to regs BEFORE
// next-stage loads are issued (FIFO vmcnt: keeps DMAs in flight across MFMAs).
template <bool CELL_BF16>
__global__ __launch_bounds__(256, 4) void edge_mlp(
    const float* __restrict__ cell_f32,
    const unsigned short* __restrict__ cellb,
    const float* __restrict__ edge_attr,
    const unsigned short* __restrict__ W1F,
    const float* __restrict__ b1,
    const unsigned short* __restrict__ W2F,
    const float* __restrict__ b2,
    const int* __restrict__ sidx,
    const int* __restrict__ ridx,
    float* __restrict__ out)
{
    __shared__ __align__(16) unsigned short sA[2][TM * D];  // 2 x 16 KB, 16B-slot XOR swizzle

    const int tid  = threadIdx.x;
    const int lane = tid & 63;
    const int wave = tid >> 6;     // = wn (col strip)
    const int l16  = lane & 15;
    const int q    = lane >> 4;
    const int e0   = blockIdx.x * TM;
    const int rb   = tid >> 4;     // 0..15
    const int seg  = tid & 15;

    // ---- stage a gathered cell chunk into buf (swizzled: slot s holds seg s^(row&7)) ----
    auto stage_cell = [&](const int* __restrict__ idxp, unsigned short* buf) {
        if constexpr (CELL_BF16) {
#pragma unroll
            for (int it = 0; it < 4; ++it) {
                const int row = it * 16 + wave * 4 + q;          // lane's row
                const int node = idxp[e0 + row];
                const int srcoff = (l16 ^ (row & 7)) * 8;        // elems
                gl_lds16(cellb + (size_t)node * D + srcoff,
                         (char*)buf + wave * 1024 + it * 4096);  // wave-uniform dest base
            }
        } else {
#pragma unroll
            for (int it = 0; it < 4; ++it) {
                const int row = rb + it * 16;
                const int node = idxp[e0 + row];
                const float* src = cell_f32 + (size_t)node * D + seg * 8;
                float4 f0 = *(const float4*)src;
                float4 f1 = *(const float4*)(src + 4);
                uint4 v = make_uint4(pk2(f0.x, f0.y), pk2(f0.z, f0.w),
                                     pk2(f1.x, f1.y), pk2(f1.z, f1.w));
                *(uint4*)((char*)buf + row * 256 + ((seg ^ (row & 7)) * 16)) = v;
            }
        }
    };

    // ---- W1 frag prefetch for chunk c (8 frags = 32 VGPRs) ----
    short8 wf[4][2];
    auto load_w1 = [&](int c) {
#pragma unroll
        for (int kk = 0; kk < 4; ++kk)
#pragma unroll
            for (int nt = 0; nt < 2; ++nt)
                wf[kk][nt] = *(const short8*)(W1F +
                    (size_t)(((c * 4 + kk) * 8 + wave * 2 + nt) * 64 + lane) * 8);
    };

    f32x4 acc[4][2];
#pragma unroll
    for (int i = 0; i < 4; ++i)
#pragma unroll
        for (int j = 0; j < 2; ++j) acc[i][j] = (f32x4){0.f, 0.f, 0.f, 0.f};

    // ---- MFMA over one 64x128-K chunk, frags read inline from buf ----
    auto compute_chunk = [&](const unsigned short* buf) {
#pragma unroll
        for (int kk = 0; kk < 4; ++kk)
#pragma unroll
            for (int mt = 0; mt < 4; ++mt) {
                const int row = mt * 16 + l16;
                short8 a = *(const short8*)((const char*)buf + row * 256 +
                                            (((kk * 4 + q) ^ (row & 7)) * 16));
                acc[mt][0] = __builtin_amdgcn_mfma_f32_16x16x32_bf16(wf[kk][0], a, acc[mt][0], 0, 0, 0);
                acc[mt][1] = __builtin_amdgcn_mfma_f32_16x16x32_bf16(wf[kk][1], a, acc[mt][1], 0, 0, 0);
            }
    };

    // ============ phase 0: stage senders -> buf0 ============
    stage_cell(sidx, sA[0]);
    __syncthreads();

    // ============ phase 1: compute S (c=0) | DMA receivers -> buf1 ============
    load_w1(0);                    // W-frags FIRST (older than DMA in vmcnt FIFO)
    stage_cell(ridx, sA[1]);       // DMAs stay in flight under the MFMAs
    compute_chunk(sA[0]);
    __syncthreads();               // drains DMA; buf0 free

    // ============ phase 2: compute R (c=1) | edge loads in regs ============
    load_w1(1);
    float4 ef0[4], ef1[4];
#pragma unroll
    for (int it = 0; it < 4; ++it) {
        const float* src = edge_attr + (size_t)(e0 + rb + it * 16) * D + seg * 8;
        ef0[it] = *(const float4*)src;
        ef1[it] = *(const float4*)(src + 4);
    }
    compute_chunk(sA[1]);
    // convert + write edge chunk -> buf0 (write-late: HBM latency hid under MFMAs)
#pragma unroll
    for (int it = 0; it < 4; ++it) {
        const int row = rb + it * 16;
        uint4 v = make_uint4(pk2(ef0[it].x, ef0[it].y), pk2(ef0[it].z, ef0[it].w),
                             pk2(ef1[it].x, ef1[it].y), pk2(ef1[it].z, ef1[it].w));
        *(uint4*)((char*)sA[0] + row * 256 + ((seg ^ (row & 7)) * 16)) = v;
    }
    __syncthreads();               // edge chunk ready; buf1 free

    // ============ phase 3: compute E (c=2); h -> buf1 ============
    load_w1(2);
    compute_chunk(sA[0]);

    // prefetch W2 frags (latency hidden under h epilogue + barrier)
    short8 w2f[4][2];
#pragma unroll
    for (int kk = 0; kk < 4; ++kk)
#pragma unroll
        for (int nt = 0; nt < 2; ++nt)
            w2f[kk][nt] = *(const short8*)(W2F +
                (size_t)((kk * 8 + wave * 2 + nt) * 64 + lane) * 8);

    f32x4 b1v[2];
#pragma unroll
    for (int nt = 0; nt < 2; ++nt)
        b1v[nt] = *(const f32x4*)(b1 + wave * 32 + nt * 16 + q * 4);

    // h = relu(acc + b1) -> buf1, packed 8B swizzled writes
#pragma unroll
    for (int mt = 0; mt < 4; ++mt)
#pragma unroll
        for (int nt = 0; nt < 2; ++nt) {
            f32x4 v = acc[mt][nt] + b1v[nt];
#pragma unroll
            for (int r = 0; r < 4; ++r) v[r] = v[r] > 0.f ? v[r] : 0.f;
            const int M = mt * 16 + l16;
            const int slot = (wave * 4 + nt * 2 + (q >> 1)) ^ (M & 7);
            *(uint2*)((char*)sA[1] + M * 256 + slot * 16 + (q & 1) * 8) =
                make_uint2(pk2(v[0], v[1]), pk2(v[2], v[3]));
        }
    __syncthreads();               // h complete

    // ============ phase 4: GEMM2 out = h @ W2 + b2 ============
    f32x4 acc2[4][2];
#pragma unroll
    for (int i = 0; i < 4; ++i)
#pragma unroll
        for (int j = 0; j < 2; ++j) acc2[i][j] = (f32x4){0.f, 0.f, 0.f, 0.f};

#pragma unroll
    for (int kk = 0; kk < 4; ++kk)
#pragma unroll
        for (int mt = 0; mt < 4; ++mt) {
            const int row = mt * 16 + l16;
            short8 h = *(const short8*)((const char*)sA[1] + row * 256 +
                                        (((kk * 4 + q) ^ (row & 7)) * 16));
            acc2[mt][0] = __builtin_amdgcn_mfma_f32_16x16x32_bf16(w2f[kk][0], h, acc2[mt][0], 0, 0, 0);
            acc2[mt][1] = __builtin_amdgcn_mfma_f32_16x16x32_bf16(w2f[kk][1], h, acc2[mt][1], 0, 0, 0);
        }

    f32x4 b2v[2];
#pragma unroll
    for (int nt = 0; nt < 2; ++nt)
        b2v[nt] = *(const f32x4*)(b2 + wave * 32 + nt * 16 + q * 4);

#pragma unroll
    for (int mt = 0; mt < 4; ++mt)
#pragma unroll
        for (int nt = 0; nt < 2; ++nt) {
            f32x4 o = acc2[mt][nt] + b2v[nt];
            *(f32x4*)(out + (size_t)(e0 + mt * 16 + l16) * D + wave * 32 + nt * 16 + q * 4) = o;
        }
}

extern "C" void kernel_launch(void* const* d_in, const int* in_sizes, int n_in,
                              void* d_out, int out_size, void* d_ws, size_t ws_size,
                              hipStream_t stream) {
    const float* cell = (const float*)d_in[0];
    const float* edge = (const float*)d_in[1];
    const float* W1   = (const float*)d_in[2];
    const float* b1   = (const float*)d_in[3];
    const float* W2   = (const float*)d_in[4];
    const float* b2   = (const float*)d_in[5];
    const int*   eidx = (const int*)d_in[6];

    const size_t cell_bytes = (size_t)N_NODES * D * 2;      // 12.8 MB
    const size_t w1f_bytes  = (size_t)K1 * D * 2;           // 98304
    const size_t w2f_bytes  = (size_t)D * D * 2;            // 32768

    bool cell_in_ws = ws_size >= cell_bytes + w1f_bytes + w2f_bytes;
    unsigned short* cellb;
    unsigned short* W1F;
    if (cell_in_ws) {
        cellb = (unsigned short*)d_ws;
        W1F   = (unsigned short*)((char*)d_ws + cell_bytes);
    } else {
        cellb = nullptr;
        W1F   = (unsigned short*)d_ws;
    }
    unsigned short* W2F = W1F + K1 * D;

    if (cell_in_ws) {
        int n4 = N_NODES * D / 4;   // 1.6M float4s
        prep_cell<<<(n4 + 255) / 256, 256, 0, stream>>>(cell, cellb, n4);
    }
    prep_w<<<(K1 * D + D * D) / 256, 256, 0, stream>>>(W1, W2, W1F, W2F);

    const int* sidx = eidx;
    const int* ridx = eidx + N_EDGES;
    if (cell_in_ws) {
        edge_mlp<true><<<N_EDGES / TM, 256, 0, stream>>>(
            cell, cellb, edge, W1F, b1, W2F, b2, sidx, ridx, (float*)d_out);
    } else {
        edge_mlp<false><<<N_EDGES / TM, 256, 0, stream>>>(
            cell, cellb, edge, W1F, b1, W2F, b2, sidx, ridx, (float*)d_out);
    }
}